// Round 9
// baseline (1805.071 us; speedup 1.0000x reference)
//
#include <hip/hip_runtime.h>
#include <hip/hip_cooperative_groups.h>
#include <math.h>

namespace cg = cooperative_groups;

// Heat equation, persistent cooperative kernel: 256 blocks x 1024 threads
// (1 block/CU, all co-resident), grid.sync() between K-blocks of 16 steps.
// Geometry per block: 64x64 core + 16 halo -> 96x96 LDS tile, stride 96,
// double buffered (73.7 KB). Between K-blocks only the halo ring (1280 of
// 2304 quads) is reloaded from the just-written frame; the core stays in
// LDS/registers (all core slots have margin >= 15 -> exact after 16 steps).
// Shrinking-validity window skips retired slots. Frame stores are issued
// inline from registers; in-step barriers drain lgkmcnt only. Before each
// grid.sync(): vmcnt(0) + __threadfence() for cross-XCD visibility.

#define CORE 64
#define HALO 16
#define REG  96            // CORE + 2*HALO
#define TPB  1024
#define NQ   24            // float4 quads per tile row
#define NIT  (94 * NQ)     // 2256 interior quads per step
#define NRQ  1280          // halo-ring quads (2304 - 16x16 core quads)

#define BAR() do { \
    asm volatile("s_waitcnt lgkmcnt(0)" ::: "memory"); \
    __builtin_amdgcn_s_barrier(); \
    __builtin_amdgcn_sched_barrier(0); \
} while (0)

// strict-interior load (u0 path): element taken only if strictly inside
__device__ __forceinline__ float4 load_quad_strict(const float* __restrict__ fp,
                                                   int gr, int gc0, int nX) {
    float4 v = make_float4(0.f, 0.f, 0.f, 0.f);
    if (gr > 0 && gr < nX - 1) {
        const float* sp = fp + (size_t)gr * nX + gc0;
        if (gc0 > 0 && gc0 + 3 < nX - 1) {
            v = *reinterpret_cast<const float4*>(sp);
        } else {
            if (gc0     > 0 && gc0     < nX - 1) v.x = sp[0];
            if (gc0 + 1 > 0 && gc0 + 1 < nX - 1) v.y = sp[1];
            if (gc0 + 2 > 0 && gc0 + 2 < nX - 1) v.z = sp[2];
            if (gc0 + 3 > 0 && gc0 + 3 < nX - 1) v.w = sp[3];
        }
    }
    return v;
}

// domain-clamp load (frame path): frames already carry zero boundaries
__device__ __forceinline__ float4 load_quad_domain(const float* __restrict__ fp,
                                                   int gr, int gc0, int nX) {
    float4 v = make_float4(0.f, 0.f, 0.f, 0.f);
    if (gr >= 0 && gr < nX) {
        const float* sp = fp + (size_t)gr * nX + gc0;
        if (gc0 >= 0 && gc0 + 3 < nX) {
            v = *reinterpret_cast<const float4*>(sp);
        } else {
            if (gc0     >= 0 && gc0     < nX) v.x = sp[0];
            if (gc0 + 1 >= 0 && gc0 + 1 < nX) v.y = sp[1];
            if (gc0 + 2 >= 0 && gc0 + 2 < nX) v.z = sp[2];
            if (gc0 + 3 >= 0 && gc0 + 3 < nX) v.w = sp[3];
        }
    }
    return v;
}

__device__ __forceinline__ void slot_init(int it, int o_r, int o_c, int nX,
                                          int& a, int& off, bool& st, float4& m,
                                          int& margin) {
    const int r = 1 + it / NQ;
    const int q = it % NQ;
    a = r * REG + 4 * q;
    const int gr  = o_r + r;
    const int gc0 = o_c + 4 * q;
    off = gr * nX + gc0;
    st  = (r >= HALO && r < HALO + CORE && q >= HALO / 4 && q < (REG - HALO) / 4);
    const bool rin = (gr > 0 && gr < nX - 1);
    m.x = (rin && gc0     > 0 && gc0     < nX - 1) ? 1.f : 0.f;
    m.y = (rin && gc0 + 1 > 0 && gc0 + 1 < nX - 1) ? 1.f : 0.f;
    m.z = (rin && gc0 + 2 > 0 && gc0 + 2 < nX - 1) ? 1.f : 0.f;
    m.w = (rin && gc0 + 3 > 0 && gc0 + 3 < nX - 1) ? 1.f : 0.f;
    margin = min(min(r - 1, 94 - r), min(4 * q + 2, 94 - 4 * q));
}

__device__ __forceinline__ void step_one(const float* __restrict__ bc,
                                         float* __restrict__ bn,
                                         float* __restrict__ of,
                                         int a, int off, bool st,
                                         const float4& m, float4& c, float gamma) {
    const float4 u4 = *reinterpret_cast<const float4*>(bc + a - REG);
    const float4 d4 = *reinterpret_cast<const float4*>(bc + a + REG);
    const float lf = bc[a - 1];
    const float rt = bc[a + 4];
    float4 o;
    o.x = m.x * (c.x + gamma * (u4.x + d4.x + lf  + c.y - 4.f * c.x));
    o.y = m.y * (c.y + gamma * (u4.y + d4.y + c.x + c.z - 4.f * c.y));
    o.z = m.z * (c.z + gamma * (u4.z + d4.z + c.y + c.w - 4.f * c.z));
    o.w = m.w * (c.w + gamma * (u4.w + d4.w + c.z + rt  - 4.f * c.w));
    *reinterpret_cast<float4*>(bn + a) = o;
    if (st) *reinterpret_cast<float4*>(of + off) = o;
    c = o;   // this step's output is next step's center
}

__global__ __launch_bounds__(TPB)
void heat_persist(const float* __restrict__ u0,
                  float* __restrict__ out,
                  int nX, int ts,
                  const float* __restrict__ alpha_p,
                  const int* __restrict__ T_p) {
    __shared__ float buf[2][REG * REG];
    cg::grid_group grid = cg::this_grid();

    const int tid = threadIdx.x;
    const int gb  = nX / CORE;                 // 16
    const int bx  = blockIdx.x % gb;
    const int by  = blockIdx.x / gb;
    const int o_r = by * CORE - HALO;
    const int o_c = bx * CORE - HALO;
    const size_t n0 = (size_t)nX * nX;

    const float alpha = *alpha_p;
    const float Tf    = (float)(*T_p);
    const float dx    = 6.0f / (float)(nX - 1);
    const float dt    = Tf / (float)(ts - 1);
    const float gamma = alpha * dt / (dx * dx);

    // ---- initial 96x96 tile load from u0 (strict interior mask) and
    //      inline store of reference frame 0 (core quads cover the domain)
    for (int qi = tid; qi < REG * NQ; qi += TPB) {
        const int r = qi / NQ, q = qi % NQ;
        const int gr = o_r + r, gc0 = o_c + 4 * q;
        const float4 v = load_quad_strict(u0, gr, gc0, nX);
        *reinterpret_cast<float4*>(&buf[0][r * REG + 4 * q]) = v;
        if (r >= HALO && r < HALO + CORE && q >= HALO / 4 && q < (REG - HALO) / 4)
            *reinterpret_cast<float4*>(out + (size_t)gr * nX + gc0) = v;
    }
    BAR();

    // ---- per-slot invariants, hoisted across ALL 255 steps ----
    int a0, a1, a2 = REG, off0, off1, off2 = 0, mg0, mg1, mg2 = -1;
    bool st0, st1, st2 = false;
    float4 m0, m1, m2 = make_float4(0.f, 0.f, 0.f, 0.f);
    slot_init(tid,       o_r, o_c, nX, a0, off0, st0, m0, mg0);
    slot_init(tid + TPB, o_r, o_c, nX, a1, off1, st1, m1, mg1);
    const bool has2 = (tid + 2 * TPB) < NIT;
    if (has2) slot_init(tid + 2 * TPB, o_r, o_c, nX, a2, off2, st2, m2, mg2);

    float4 c0 = *reinterpret_cast<const float4*>(&buf[0][a0]);
    float4 c1 = *reinterpret_cast<const float4*>(&buf[0][a1]);
    float4 c2 = make_float4(0.f, 0.f, 0.f, 0.f);
    if (has2) c2 = *reinterpret_cast<const float4*>(&buf[0][a2]);

    for (int t = 0; t < ts - 1; t += HALO) {
        const int k = min(HALO, ts - 1 - t);

        for (int s = 0; s < k; ++s) {
            const float* __restrict__ bc = buf[s & 1];
            float*       __restrict__ bn = buf[(s & 1) ^ 1];
            float* of = out + (size_t)(t + s + 1) * n0;
            if (s <= mg0) step_one(bc, bn, of, a0, off0, st0, m0, c0, gamma);
            if (s <= mg1) step_one(bc, bn, of, a1, off1, st1, m1, c1, gamma);
            if (s <= mg2) step_one(bc, bn, of, a2, off2, st2, m2, c2, gamma);
            BAR();
        }

        if (t + HALO < ts - 1) {
            // make frame t+16 globally visible, then refresh the halo ring
            asm volatile("s_waitcnt vmcnt(0)" ::: "memory");
            __threadfence();
            grid.sync();

            const float* fp = out + (size_t)(t + HALO) * n0;
            #pragma unroll
            for (int it2 = 0; it2 < 2; ++it2) {
                const int idx = tid + it2 * TPB;
                if (idx < NRQ) {
                    int r, q;
                    if (idx < 768) {                 // top/bottom 16-row bands
                        const int rr = idx / NQ;     // 0..31
                        r = (rr < 16) ? rr : rr + 64;
                        q = idx % NQ;
                    } else {                         // side 16-col bands
                        const int e = idx - 768;     // 0..511
                        r = 16 + (e >> 3);
                        const int qq = e & 7;
                        q = (qq < 4) ? qq : qq + 16;
                    }
                    const float4 v = load_quad_domain(fp, o_r + r, o_c + 4 * q, nX);
                    *reinterpret_cast<float4*>(&buf[0][r * REG + 4 * q]) = v;
                }
            }
            BAR();
            // core slots keep register-carried centers (LDS core untouched);
            // ring slots re-read theirs from the refreshed tile
            if (!st0) c0 = *reinterpret_cast<const float4*>(&buf[0][a0]);
            if (!st1) c1 = *reinterpret_cast<const float4*>(&buf[0][a1]);
            if (has2 && !st2) c2 = *reinterpret_cast<const float4*>(&buf[0][a2]);
        }
    }
}

extern "C" void kernel_launch(void* const* d_in, const int* in_sizes, int n_in,
                              void* d_out, int out_size, void* d_ws, size_t ws_size,
                              hipStream_t stream) {
    const float* u0      = (const float*)d_in[0];
    const float* alpha_p = (const float*)d_in[1];
    const int*   T_p     = (const int*)d_in[2];

    const int n0 = in_sizes[0];                   // nX*nX
    int nX = (int)(sqrtf((float)n0) + 0.5f);
    int ts = out_size / n0;                       // time_steps

    float* out = (float*)d_out;
    const int gb = nX / CORE;                     // 16
    int nblocks = gb * gb;                        // 256 = 1 block/CU

    void* args[] = {(void*)&u0, (void*)&out, (void*)&nX, (void*)&ts,
                    (void*)&alpha_p, (void*)&T_p};
    hipLaunchCooperativeKernel((void*)heat_persist, dim3(nblocks), dim3(TPB),
                               args, 0, stream);
}

// Round 10
// 299.868 us; speedup vs baseline: 6.0196x; 6.0196x over previous
//
#include <hip/hip_runtime.h>
#include <math.h>

// Heat equation, temporally blocked, K=16 steps/launch, 16 dispatches.
// Round 9: revert to round-8 multi-dispatch structure (cooperative grid.sync
// measured ~100us/sync on this stack -> abandoned) and fix what the R9
// counters showed:
//  - SQ_LDS_BANK_CONFLICT=2.3e7 with stride 96 (96%32==0: every row bank-
//    aligned) -> pad LDS row stride to 100 floats (100%32=4 rotates banks).
//    Pad cols + buf[1] edge rows zeroed once (NaN-proof; window argument
//    keeps pad junk out of the stored core).
//  - init kernel folded into dispatch 0 (strict-interior load serves both
//    u0 and frames: frames carry zero boundaries; frame 0 stored inline).
// Geometry: 64x64 core + 16 halo -> 96x96 tile, double buffered (76.8 KB),
// 1024 threads, shrinking validity window, register-carried centers,
// inline register->global frame stores, barriers drain lgkmcnt only.

#define CORE 64
#define HALO 16
#define REG  96            // logical tile side
#define PAD  100           // padded LDS row stride in floats
#define TPB  1024
#define NQ   24            // data quads per tile row
#define ROWQ 25            // quads per padded row (incl. 1 pad quad)
#define NIT  (94 * NQ)     // 2256 interior quads per step

#define BAR() do { \
    asm volatile("s_waitcnt lgkmcnt(0)" ::: "memory"); \
    __builtin_amdgcn_s_barrier(); \
    __builtin_amdgcn_sched_barrier(0); \
} while (0)

// strict-interior load: element taken only if strictly inside the domain.
// Valid for u0 AND for frames (frames have zero boundaries anyway).
__device__ __forceinline__ float4 load_quad_strict(const float* __restrict__ fp,
                                                   int gr, int gc0, int nX) {
    float4 v = make_float4(0.f, 0.f, 0.f, 0.f);
    if (gr > 0 && gr < nX - 1) {
        const float* sp = fp + (size_t)gr * nX + gc0;
        if (gc0 > 0 && gc0 + 3 < nX - 1) {
            v = *reinterpret_cast<const float4*>(sp);
        } else {
            if (gc0     > 0 && gc0     < nX - 1) v.x = sp[0];
            if (gc0 + 1 > 0 && gc0 + 1 < nX - 1) v.y = sp[1];
            if (gc0 + 2 > 0 && gc0 + 2 < nX - 1) v.z = sp[2];
            if (gc0 + 3 > 0 && gc0 + 3 < nX - 1) v.w = sp[3];
        }
    }
    return v;
}

__device__ __forceinline__ void slot_init(int it, int o_r, int o_c, int nX,
                                          int& a, int& off, bool& st, float4& m,
                                          int& margin) {
    const int r = 1 + it / NQ;
    const int q = it % NQ;
    a = r * PAD + 4 * q;
    const int gr  = o_r + r;
    const int gc0 = o_c + 4 * q;
    off = gr * nX + gc0;
    st  = (r >= HALO && r < HALO + CORE && q >= HALO / 4 && q < (REG - HALO) / 4);
    const bool rin = (gr > 0 && gr < nX - 1);
    m.x = (rin && gc0     > 0 && gc0     < nX - 1) ? 1.f : 0.f;
    m.y = (rin && gc0 + 1 > 0 && gc0 + 1 < nX - 1) ? 1.f : 0.f;
    m.z = (rin && gc0 + 2 > 0 && gc0 + 2 < nX - 1) ? 1.f : 0.f;
    m.w = (rin && gc0 + 3 > 0 && gc0 + 3 < nX - 1) ? 1.f : 0.f;
    // slot can still influence stored output while s <= margin
    margin = min(min(r - 1, 94 - r), min(4 * q + 2, 94 - 4 * q));
}

__device__ __forceinline__ void step_one(const float* __restrict__ bc,
                                         float* __restrict__ bn,
                                         float* __restrict__ of,
                                         int a, int off, bool st,
                                         const float4& m, float4& c, float gamma) {
    const float4 u4 = *reinterpret_cast<const float4*>(bc + a - PAD);
    const float4 d4 = *reinterpret_cast<const float4*>(bc + a + PAD);
    const float lf = bc[a - 1];
    const float rt = bc[a + 4];
    float4 o;
    o.x = m.x * (c.x + gamma * (u4.x + d4.x + lf  + c.y - 4.f * c.x));
    o.y = m.y * (c.y + gamma * (u4.y + d4.y + c.x + c.z - 4.f * c.y));
    o.z = m.z * (c.z + gamma * (u4.z + d4.z + c.y + c.w - 4.f * c.z));
    o.w = m.w * (c.w + gamma * (u4.w + d4.w + c.z + rt  - 4.f * c.w));
    *reinterpret_cast<float4*>(bn + a) = o;
    if (st) *reinterpret_cast<float4*>(of + off) = o;
    c = o;   // this step's output is next step's center
}

__global__ __launch_bounds__(TPB)
void heat_fused(const float* __restrict__ src,       // u0 (first) or frame t_base
                float* __restrict__ out,             // full output base
                int t_base, int k, int nX, int first,
                int time_steps,
                const float* __restrict__ alpha_p,
                const int* __restrict__ T_p) {
    __shared__ float buf[2][REG * PAD];

    const int tid = threadIdx.x;
    const int gb  = nX / CORE;                 // 16
    const int bx  = blockIdx.x % gb;
    const int by  = blockIdx.x / gb;
    const int o_r = by * CORE - HALO;
    const int o_c = bx * CORE - HALO;
    const size_t n0 = (size_t)nX * nX;

    const float alpha = *alpha_p;
    const float Tf    = (float)(*T_p);
    const float dx    = 6.0f / (float)(nX - 1);
    const float dt    = Tf / (float)(time_steps - 1);
    const float gamma = alpha * dt / (dx * dx);

    const float4 z4 = make_float4(0.f, 0.f, 0.f, 0.f);

    // ---- load 96x96 tile (strict interior mask). Pad cols of BOTH buffers
    // and edge rows of buf[1] zeroed (NaN-proof). first==1: store frame 0.
    for (int qi = tid; qi < REG * ROWQ; qi += TPB) {
        const int r = qi / ROWQ, q = qi % ROWQ;
        const int a = r * PAD + 4 * q;
        if (q == NQ) {                           // pad quad (cols 96..99)
            *reinterpret_cast<float4*>(&buf[0][a]) = z4;
            *reinterpret_cast<float4*>(&buf[1][a]) = z4;
            continue;
        }
        const int gr = o_r + r, gc0 = o_c + 4 * q;
        const float4 v = load_quad_strict(src, gr, gc0, nX);
        *reinterpret_cast<float4*>(&buf[0][a]) = v;
        if (r == 0 || r == REG - 1)              // buf[1] edge rows never written
            *reinterpret_cast<float4*>(&buf[1][a]) = z4;
        if (first && r >= HALO && r < HALO + CORE && q >= HALO / 4 && q < (REG - HALO) / 4)
            *reinterpret_cast<float4*>(out + (size_t)gr * nX + gc0) = v;   // frame 0
    }
    BAR();

    // ---- per-slot loop invariants ----
    int a0, a1, a2 = PAD, off0, off1, off2 = 0, mg0, mg1, mg2 = -1;
    bool st0, st1, st2 = false;
    float4 m0, m1, m2 = z4;
    slot_init(tid,       o_r, o_c, nX, a0, off0, st0, m0, mg0);
    slot_init(tid + TPB, o_r, o_c, nX, a1, off1, st1, m1, mg1);
    const bool has2 = (tid + 2 * TPB) < NIT;
    if (has2) slot_init(tid + 2 * TPB, o_r, o_c, nX, a2, off2, st2, m2, mg2);

    float4 c0 = *reinterpret_cast<const float4*>(&buf[0][a0]);
    float4 c1 = *reinterpret_cast<const float4*>(&buf[0][a1]);
    float4 c2 = z4;
    if (has2) c2 = *reinterpret_cast<const float4*>(&buf[0][a2]);

    for (int s = 0; s < k; ++s) {
        const float* __restrict__ bc = buf[s & 1];
        float*       __restrict__ bn = buf[(s & 1) ^ 1];
        float* of = out + (size_t)(t_base + s + 1) * n0;

        if (s <= mg0) step_one(bc, bn, of, a0, off0, st0, m0, c0, gamma);
        if (s <= mg1) step_one(bc, bn, of, a1, off1, st1, m1, c1, gamma);
        if (s <= mg2) step_one(bc, bn, of, a2, off2, st2, m2, c2, gamma);

        // LDS-only drain; global stores remain in flight across the barrier
        BAR();
    }
}

extern "C" void kernel_launch(void* const* d_in, const int* in_sizes, int n_in,
                              void* d_out, int out_size, void* d_ws, size_t ws_size,
                              hipStream_t stream) {
    const float* u0      = (const float*)d_in[0];
    const float* alpha_p = (const float*)d_in[1];
    const int*   T_p     = (const int*)d_in[2];

    const int n0 = in_sizes[0];                   // nX*nX
    const int nX = (int)(sqrtf((float)n0) + 0.5f);
    const int ts = out_size / n0;                 // time_steps

    float* out = (float*)d_out;
    const int gb = nX / CORE;                     // 16
    const int nblocks = gb * gb;                  // 256 = 1 block/CU

    for (int t = 0; t < ts - 1; t += HALO) {
        const int k = min(HALO, ts - 1 - t);
        const float* src = (t == 0) ? u0 : out + (size_t)t * n0;
        heat_fused<<<nblocks, TPB, 0, stream>>>(src, out, t, k, nX,
                                                (t == 0) ? 1 : 0, ts,
                                                alpha_p, T_p);
    }
}

// Round 11
// 284.261 us; speedup vs baseline: 6.3501x; 1.0549x over previous
//
#include <hip/hip_runtime.h>
#include <math.h>

// Heat equation, temporally blocked, K=16 steps/launch, 16+1 dispatches.
// Round 10: R7 base (282us best: stride-96 LDS, separate init, shrinking
// window, vectorized load) + VERTICAL PAIR SLOTS: each unit owns two
// stacked quads (rows r0,r0+1). Inner vertical neighbors come from the
// pair's center registers -> 2 of 4 ds_read_b128 per 2 quads eliminated
// (the measured critical path was the per-step LDS chain, 12.2us > 10.3us
// write stream). Per-row retire guards keep the validity-window argument.

#define CORE 64
#define HALO 16
#define REG  96            // tile side, LDS row stride
#define TPB  1024
#define NQ   24            // float4 quads per tile row
#define NU   (47 * NQ)     // 1128 pair-units (rows 1..94 in 47 pairs)

#define BAR() do { \
    asm volatile("s_waitcnt lgkmcnt(0)" ::: "memory"); \
    __builtin_amdgcn_s_barrier(); \
    __builtin_amdgcn_sched_barrier(0); \
} while (0)

__global__ __launch_bounds__(256)
void heat_init(const float* __restrict__ u0, float* __restrict__ out, int nX) {
    const int row = blockIdx.x;
    const int j   = threadIdx.x;
    const int nq  = nX >> 2;
    float4* dst = reinterpret_cast<float4*>(out + (size_t)row * nX);
    if (row == 0 || row == nX - 1) {
        dst[j] = make_float4(0.f, 0.f, 0.f, 0.f);
        return;
    }
    const float4* src = reinterpret_cast<const float4*>(u0 + (size_t)row * nX);
    float4 v = src[j];
    if (j == 0)      v.x = 0.f;
    if (j == nq - 1) v.w = 0.f;
    dst[j] = v;
}

__device__ __forceinline__ float4 mask_of(int gr, int gc0, int nX) {
    float4 m;
    const bool rin = (gr > 0 && gr < nX - 1);
    m.x = (rin && gc0     > 0 && gc0     < nX - 1) ? 1.f : 0.f;
    m.y = (rin && gc0 + 1 > 0 && gc0 + 1 < nX - 1) ? 1.f : 0.f;
    m.z = (rin && gc0 + 2 > 0 && gc0 + 2 < nX - 1) ? 1.f : 0.f;
    m.w = (rin && gc0 + 3 > 0 && gc0 + 3 < nX - 1) ? 1.f : 0.f;
    return m;
}

struct PairSlot {
    int a;          // LDS addr of row r0's quad
    int off;        // global elem offset of row r0's quad (within a frame)
    bool st0, st1;  // core-store predicates per row
    int mg0, mg1;   // validity margins per row
    float4 m0, m1;  // boundary masks per row
    float4 c0, c1;  // center registers per row
};

__device__ __forceinline__ void pair_init(int u, int o_r, int o_c, int nX,
                                          PairSlot& p) {
    const int pr = u / NQ;             // 0..46
    const int q  = u % NQ;             // 0..23
    const int r0 = 1 + 2 * pr;         // 1,3,..,93
    p.a = r0 * REG + 4 * q;
    const int gr0 = o_r + r0;
    const int gc0 = o_c + 4 * q;
    p.off = gr0 * nX + gc0;
    const bool qc = (q >= HALO / 4 && q < (REG - HALO) / 4);
    p.st0 = (r0     >= HALO && r0     < HALO + CORE && qc);
    p.st1 = (r0 + 1 >= HALO && r0 + 1 < HALO + CORE && qc);
    p.m0 = mask_of(gr0,     gc0, nX);
    p.m1 = mask_of(gr0 + 1, gc0, nX);
    const int colm = min(4 * q + 2, 94 - 4 * q);
    p.mg0 = min(min(r0 - 1, 94 - r0), colm);
    p.mg1 = min(min(r0, 93 - r0), colm);
}

__device__ __forceinline__ void pair_step(const float* __restrict__ bc,
                                          float* __restrict__ bn,
                                          float* __restrict__ of,
                                          PairSlot& p, float gamma,
                                          int nX, int s) {
    const float4 u4 = *reinterpret_cast<const float4*>(bc + p.a - REG);
    const float4 d4 = *reinterpret_cast<const float4*>(bc + p.a + 2 * REG);
    const float lf0 = bc[p.a - 1];
    const float rt0 = bc[p.a + 4];
    const float lf1 = bc[p.a + REG - 1];
    const float rt1 = bc[p.a + REG + 4];
    const float4 c0 = p.c0, c1 = p.c1;   // old values for both rows

    float4 o0, o1;
    o0.x = p.m0.x * (c0.x + gamma * (u4.x + c1.x + lf0  + c0.y - 4.f * c0.x));
    o0.y = p.m0.y * (c0.y + gamma * (u4.y + c1.y + c0.x + c0.z - 4.f * c0.y));
    o0.z = p.m0.z * (c0.z + gamma * (u4.z + c1.z + c0.y + c0.w - 4.f * c0.z));
    o0.w = p.m0.w * (c0.w + gamma * (u4.w + c1.w + c0.z + rt0  - 4.f * c0.w));

    o1.x = p.m1.x * (c1.x + gamma * (c0.x + d4.x + lf1  + c1.y - 4.f * c1.x));
    o1.y = p.m1.y * (c1.y + gamma * (c0.y + d4.y + c1.x + c1.z - 4.f * c1.y));
    o1.z = p.m1.z * (c1.z + gamma * (c0.z + d4.z + c1.y + c1.w - 4.f * c1.z));
    o1.w = p.m1.w * (c1.w + gamma * (c0.w + d4.w + c1.z + rt1  - 4.f * c1.w));

    if (s <= p.mg0) {
        *reinterpret_cast<float4*>(bn + p.a) = o0;
        if (p.st0) *reinterpret_cast<float4*>(of + p.off) = o0;
        p.c0 = o0;
    }
    if (s <= p.mg1) {
        *reinterpret_cast<float4*>(bn + p.a + REG) = o1;
        if (p.st1) *reinterpret_cast<float4*>(of + p.off + nX) = o1;
        p.c1 = o1;
    }
}

__global__ __launch_bounds__(TPB)
void heat_fused(const float* __restrict__ src,       // frame t_base
                float* __restrict__ out,             // full output base
                int t_base, int k, int nX, int time_steps,
                const float* __restrict__ alpha_p,
                const int* __restrict__ T_p) {
    __shared__ float buf[2][REG * REG];

    const int tid = threadIdx.x;
    const int gb  = nX / CORE;                 // 16
    const int bx  = blockIdx.x % gb;
    const int by  = blockIdx.x / gb;
    const int o_r = by * CORE - HALO;
    const int o_c = bx * CORE - HALO;
    const size_t n0 = (size_t)nX * nX;

    const float alpha = *alpha_p;
    const float Tf    = (float)(*T_p);
    const float dx    = 6.0f / (float)(nX - 1);
    const float dt    = Tf / (float)(time_steps - 1);
    const float gamma = alpha * dt / (dx * dx);

    // ---- load 96x96 tile of frame t_base, float4-vectorized ----
    for (int qi = tid; qi < REG * NQ; qi += TPB) {
        const int r = qi / NQ, q = qi % NQ;
        const int gr = o_r + r, gc0 = o_c + 4 * q;
        float4 v = make_float4(0.f, 0.f, 0.f, 0.f);
        if (gr >= 0 && gr < nX) {
            const float* sp = src + (size_t)gr * nX + gc0;
            if (gc0 >= 0 && gc0 + 3 < nX) {
                v = *reinterpret_cast<const float4*>(sp);   // fast path
            } else {
                if (gc0     >= 0 && gc0     < nX) v.x = sp[0];
                if (gc0 + 1 >= 0 && gc0 + 1 < nX) v.y = sp[1];
                if (gc0 + 2 >= 0 && gc0 + 2 < nX) v.z = sp[2];
                if (gc0 + 3 >= 0 && gc0 + 3 < nX) v.w = sp[3];
            }
        }
        *reinterpret_cast<float4*>(&buf[0][r * REG + 4 * q]) = v;
    }
    BAR();

    // ---- pair-units: thread tid owns unit tid; tid<104 also unit 1024+tid
    PairSlot p0, p1;
    pair_init(tid, o_r, o_c, nX, p0);
    const bool has1 = (tid + TPB) < NU;        // tid < 104
    if (has1) pair_init(tid + TPB, o_r, o_c, nX, p1);
    const int mgU0 = max(p0.mg0, p0.mg1);
    const int mgU1 = has1 ? max(p1.mg0, p1.mg1) : -1;

    p0.c0 = *reinterpret_cast<const float4*>(&buf[0][p0.a]);
    p0.c1 = *reinterpret_cast<const float4*>(&buf[0][p0.a + REG]);
    if (has1) {
        p1.c0 = *reinterpret_cast<const float4*>(&buf[0][p1.a]);
        p1.c1 = *reinterpret_cast<const float4*>(&buf[0][p1.a + REG]);
    }

    for (int s = 0; s < k; ++s) {
        const float* __restrict__ bc = buf[s & 1];
        float*       __restrict__ bn = buf[(s & 1) ^ 1];
        float* of = out + (size_t)(t_base + s + 1) * n0;

        if (s <= mgU0) pair_step(bc, bn, of, p0, gamma, nX, s);
        if (s <= mgU1) pair_step(bc, bn, of, p1, gamma, nX, s);

        // LDS-only drain; global stores remain in flight across the barrier
        BAR();
    }
}

extern "C" void kernel_launch(void* const* d_in, const int* in_sizes, int n_in,
                              void* d_out, int out_size, void* d_ws, size_t ws_size,
                              hipStream_t stream) {
    const float* u0      = (const float*)d_in[0];
    const float* alpha_p = (const float*)d_in[1];
    const int*   T_p     = (const int*)d_in[2];

    const int n0 = in_sizes[0];                   // nX*nX
    const int nX = (int)(sqrtf((float)n0) + 0.5f);
    const int ts = out_size / n0;                 // time_steps

    float* out = (float*)d_out;
    const int gb = nX / CORE;                     // 16
    const int nblocks = gb * gb;                  // 256 = 1 block/CU

    heat_init<<<nX, nX / 4, 0, stream>>>(u0, out, nX);

    for (int t = 0; t < ts - 1; t += HALO) {
        const int k = min(HALO, ts - 1 - t);
        heat_fused<<<nblocks, TPB, 0, stream>>>(out + (size_t)t * n0, out,
                                                t, k, nX, ts, alpha_p, T_p);
    }
}

// Round 12
// 276.634 us; speedup vs baseline: 6.5251x; 1.0276x over previous
//
#include <hip/hip_runtime.h>
#include <math.h>

// Heat equation, temporally blocked. Round 11: K=20 steps/launch, 13
// dispatches total (init folded into dispatch 0). Evidence: R10 cut LDS
// reads 25% -> flat, so per-dispatch time is store-stream-bound; the
// reducible term is dispatch count (gaps+loads+tails), so deepen K while
// chain/step (~0.7us) stays near write/step (~0.66us).
// Block: 64x64 core + 20 halo -> 104x104 LDS tile, stride 104 (%32=8, no
// extra pad, 26 quads/row exact), double buffered 86.5 KB, 1024 threads,
// shrinking validity window, register-carried centers, inline
// register->global frame stores, barriers drain lgkmcnt only.

#define CORE 64
#define HALO 20
#define TILE 104           // tile side AND LDS row stride
#define TPB  1024
#define NQ   26            // float4 quads per tile row
#define NIT  (102 * NQ)    // 2652 interior quads per step

#define BAR() do { \
    asm volatile("s_waitcnt lgkmcnt(0)" ::: "memory"); \
    __builtin_amdgcn_s_barrier(); \
    __builtin_amdgcn_sched_barrier(0); \
} while (0)

// strict-interior load: element taken only if strictly inside the domain.
// Valid for u0 AND frames (frames carry zero boundaries).
__device__ __forceinline__ float4 load_quad_strict(const float* __restrict__ fp,
                                                   int gr, int gc0, int nX) {
    float4 v = make_float4(0.f, 0.f, 0.f, 0.f);
    if (gr > 0 && gr < nX - 1) {
        const float* sp = fp + (size_t)gr * nX + gc0;
        if (gc0 > 0 && gc0 + 3 < nX - 1) {
            v = *reinterpret_cast<const float4*>(sp);
        } else {
            if (gc0     > 0 && gc0     < nX - 1) v.x = sp[0];
            if (gc0 + 1 > 0 && gc0 + 1 < nX - 1) v.y = sp[1];
            if (gc0 + 2 > 0 && gc0 + 2 < nX - 1) v.z = sp[2];
            if (gc0 + 3 > 0 && gc0 + 3 < nX - 1) v.w = sp[3];
        }
    }
    return v;
}

__device__ __forceinline__ void slot_init(int it, int o_r, int o_c, int nX,
                                          int& a, int& off, bool& st, float4& m,
                                          int& margin) {
    const int r = 1 + it / NQ;          // 1..102
    const int q = it % NQ;              // 0..25
    a = r * TILE + 4 * q;
    const int gr  = o_r + r;
    const int gc0 = o_c + 4 * q;
    off = gr * nX + gc0;
    st  = (r >= HALO && r < HALO + CORE && q >= HALO / 4 && q < (TILE - HALO) / 4);
    const bool rin = (gr > 0 && gr < nX - 1);
    m.x = (rin && gc0     > 0 && gc0     < nX - 1) ? 1.f : 0.f;
    m.y = (rin && gc0 + 1 > 0 && gc0 + 1 < nX - 1) ? 1.f : 0.f;
    m.z = (rin && gc0 + 2 > 0 && gc0 + 2 < nX - 1) ? 1.f : 0.f;
    m.w = (rin && gc0 + 3 > 0 && gc0 + 3 < nX - 1) ? 1.f : 0.f;
    // quad can still influence stored output while s <= margin
    margin = min(min(r - 1, 102 - r), min(4 * q + 2, 102 - 4 * q));
}

__device__ __forceinline__ void step_one(const float* __restrict__ bc,
                                         float* __restrict__ bn,
                                         float* __restrict__ of,
                                         int a, int off, bool st,
                                         const float4& m, float4& c, float gamma) {
    const float4 u4 = *reinterpret_cast<const float4*>(bc + a - TILE);
    const float4 d4 = *reinterpret_cast<const float4*>(bc + a + TILE);
    const float lf = bc[a - 1];
    const float rt = bc[a + 4];
    float4 o;
    o.x = m.x * (c.x + gamma * (u4.x + d4.x + lf  + c.y - 4.f * c.x));
    o.y = m.y * (c.y + gamma * (u4.y + d4.y + c.x + c.z - 4.f * c.y));
    o.z = m.z * (c.z + gamma * (u4.z + d4.z + c.y + c.w - 4.f * c.z));
    o.w = m.w * (c.w + gamma * (u4.w + d4.w + c.z + rt  - 4.f * c.w));
    *reinterpret_cast<float4*>(bn + a) = o;
    if (st) *reinterpret_cast<float4*>(of + off) = o;
    c = o;   // this step's output is next step's center
}

__global__ __launch_bounds__(TPB)
void heat_fused(const float* __restrict__ src,       // u0 (first) or frame t_base
                float* __restrict__ out,             // full output base
                int t_base, int k, int nX, int first,
                int time_steps,
                const float* __restrict__ alpha_p,
                const int* __restrict__ T_p) {
    __shared__ float buf[2][TILE * TILE];

    const int tid = threadIdx.x;
    const int gb  = nX / CORE;                 // 16
    const int bx  = blockIdx.x % gb;
    const int by  = blockIdx.x / gb;
    const int o_r = by * CORE - HALO;
    const int o_c = bx * CORE - HALO;
    const size_t n0 = (size_t)nX * nX;

    const float alpha = *alpha_p;
    const float Tf    = (float)(*T_p);
    const float dx    = 6.0f / (float)(nX - 1);
    const float dt    = Tf / (float)(time_steps - 1);
    const float gamma = alpha * dt / (dx * dx);

    // ---- load 104x104 tile (strict interior). first==1: store frame 0 inline.
    for (int qi = tid; qi < TILE * NQ; qi += TPB) {
        const int r = qi / NQ, q = qi % NQ;
        const int gr = o_r + r, gc0 = o_c + 4 * q;
        const float4 v = load_quad_strict(src, gr, gc0, nX);
        *reinterpret_cast<float4*>(&buf[0][r * TILE + 4 * q]) = v;
        if (first && r >= HALO && r < HALO + CORE &&
            q >= HALO / 4 && q < (TILE - HALO) / 4)
            *reinterpret_cast<float4*>(out + (size_t)gr * nX + gc0) = v; // frame 0
    }
    BAR();

    // ---- per-slot loop invariants (slots: tid, tid+1024, tid+2048) ----
    int a0, a1, a2 = TILE, off0, off1, off2 = 0, mg0, mg1, mg2 = -1;
    bool st0, st1, st2 = false;
    float4 m0, m1, m2 = make_float4(0.f, 0.f, 0.f, 0.f);
    slot_init(tid,       o_r, o_c, nX, a0, off0, st0, m0, mg0);
    slot_init(tid + TPB, o_r, o_c, nX, a1, off1, st1, m1, mg1);
    const bool has2 = (tid + 2 * TPB) < NIT;   // tid < 604
    if (has2) slot_init(tid + 2 * TPB, o_r, o_c, nX, a2, off2, st2, m2, mg2);

    float4 c0 = *reinterpret_cast<const float4*>(&buf[0][a0]);
    float4 c1 = *reinterpret_cast<const float4*>(&buf[0][a1]);
    float4 c2 = make_float4(0.f, 0.f, 0.f, 0.f);
    if (has2) c2 = *reinterpret_cast<const float4*>(&buf[0][a2]);

    for (int s = 0; s < k; ++s) {
        const float* __restrict__ bc = buf[s & 1];
        float*       __restrict__ bn = buf[(s & 1) ^ 1];
        float* of = out + (size_t)(t_base + s + 1) * n0;

        if (s <= mg0) step_one(bc, bn, of, a0, off0, st0, m0, c0, gamma);
        if (s <= mg1) step_one(bc, bn, of, a1, off1, st1, m1, c1, gamma);
        if (s <= mg2) step_one(bc, bn, of, a2, off2, st2, m2, c2, gamma);

        // LDS-only drain; global stores remain in flight across the barrier
        BAR();
    }
}

extern "C" void kernel_launch(void* const* d_in, const int* in_sizes, int n_in,
                              void* d_out, int out_size, void* d_ws, size_t ws_size,
                              hipStream_t stream) {
    const float* u0      = (const float*)d_in[0];
    const float* alpha_p = (const float*)d_in[1];
    const int*   T_p     = (const int*)d_in[2];

    const int n0 = in_sizes[0];                   // nX*nX
    const int nX = (int)(sqrtf((float)n0) + 0.5f);
    const int ts = out_size / n0;                 // time_steps

    float* out = (float*)d_out;
    const int gb = nX / CORE;                     // 16
    const int nblocks = gb * gb;                  // 256 = 1 block/CU

    for (int t = 0; t < ts - 1; t += HALO) {
        const int k = min(HALO, ts - 1 - t);
        const float* src = (t == 0) ? u0 : out + (size_t)t * n0;
        heat_fused<<<nblocks, TPB, 0, stream>>>(src, out, t, k, nX,
                                                (t == 0) ? 1 : 0, ts,
                                                alpha_p, T_p);
    }
}